// Round 3
// baseline (732.407 us; speedup 1.0000x reference)
//
#include <hip/hip_runtime.h>
#include <cstdint>
#include <cstddef>

// Problem constants
#define Bb   256
#define Tt   512
#define Ii   300
#define Hh   128
#define G4   512      // 4*H
#define KP   320      // K padded to multiple of 32 for MFMA

typedef _Float16 h2v   __attribute__((ext_vector_type(2)));
typedef _Float16 half8 __attribute__((ext_vector_type(8)));
typedef float    f32x4 __attribute__((ext_vector_type(4)));

typedef __attribute__((address_space(3))) unsigned int lds_uint;
typedef const __attribute__((address_space(1))) unsigned int glb_uint;

static __device__ __forceinline__ h2v as_h2(unsigned int u){ union{unsigned int u; h2v h;} c; c.u=u; return c.h; }
static __device__ __forceinline__ unsigned int as_u32(h2v h){ union{unsigned int u; h2v h;} c; c.h=h; return c.u; }

#if __has_builtin(__builtin_amdgcn_fdot2)
#define FDOT2(a,b,c) __builtin_amdgcn_fdot2((a),(b),(c),false)
#else
static __device__ __forceinline__ float FDOT2(h2v a, h2v b, float c){
  return c + (float)a[0]*(float)b[0] + (float)a[1]*(float)b[1];
}
#endif

// ---------------- conversion: x fp32 [131072,300] -> f16 padded [131072,320] ----------------
__global__ __launch_bounds__(256) void conv_x(const float* __restrict__ x, unsigned int* __restrict__ x16){
  int idx = blockIdx.x*256 + threadIdx.x;      // half2 index; total 131072*160, grid exact
  int r   = idx / 160;
  int kk2 = idx - r*160;
  int kk  = kk2*2;
  const float* xr = x + (size_t)r*Ii;
  float v0 = (kk   < Ii) ? xr[kk]   : 0.f;
  float v1 = (kk+1 < Ii) ? xr[kk+1] : 0.f;
  h2v h; h[0] = (_Float16)v0; h[1] = (_Float16)v1;
  x16[idx] = as_u32(h);
}

// ---------------- conversion: W_ih -> f16 padded, W_hh -> packed half2 [512][64], bias sum ----------------
__global__ __launch_bounds__(256) void conv_small(const float* __restrict__ Wih, const float* __restrict__ Whh,
      const float* __restrict__ bih, const float* __restrict__ bhh,
      unsigned int* __restrict__ W16, unsigned int* __restrict__ Whh2, float* __restrict__ bias){
  int idx = blockIdx.x*256 + threadIdx.x;
  if (idx < G4*160){
    int r = idx/160, kk2 = idx - r*160, kk = kk2*2;
    const float* wr = Wih + (size_t)r*Ii;
    float v0 = (kk   < Ii) ? wr[kk]   : 0.f;
    float v1 = (kk+1 < Ii) ? wr[kk+1] : 0.f;
    h2v h; h[0]=(_Float16)v0; h[1]=(_Float16)v1;
    W16[idx] = as_u32(h);
  } else if (idx < G4*160 + G4*64){
    int t = idx - G4*160; int j = t>>6, kk = t&63;
    float v0 = Whh[j*Hh + kk*2], v1 = Whh[j*Hh + kk*2 + 1];
    h2v h; h[0]=(_Float16)v0; h[1]=(_Float16)v1;
    Whh2[t] = as_u32(h);
  } else if (idx < G4*160 + G4*64 + G4){
    int d = idx - (G4*160 + G4*64);
    bias[d] = bih[d] + bhh[d];
  }
}

// ---------------- phase 1: xg[131072,512] = A16 @ W16^T + bias, f16 MFMA ----------------
// global_load_lds width-16 staging; XOR chunk swizzle (chunk ^= row&3) applied on the
// global source side so both DMA writes and ds_read_b128 fragment reads are conflict-free.
__global__ __launch_bounds__(256,2) void gemm16(const _Float16* __restrict__ A, const _Float16* __restrict__ Bm,
       const float* __restrict__ bias, float* __restrict__ C){
  __shared__ __align__(16) _Float16 As[128*32];
  __shared__ __align__(16) _Float16 Bs[128*32];
  int tid = threadIdx.x;
  int w = tid>>6, lane = tid&63;
  int bm = blockIdx.x*128, bn = blockIdx.y*128;
  f32x4 acc[2][8];
  #pragma unroll
  for (int i=0;i<2;i++)
    #pragma unroll
    for (int j=0;j<8;j++) acc[i][j] = (f32x4){0.f,0.f,0.f,0.f};

  // staging: chunk index L = w*128 + j*64 + lane (16B units); row=L>>2, stored chunk cs=L&3,
  // source chunk c = cs ^ (row&3)
  int L0 = w*128 + lane, L1 = L0 + 64;
  int r0 = L0>>2, c0 = (L0&3) ^ (r0&3);
  int r1 = L1>>2, c1 = (L1&3) ^ (r1&3);
  const _Float16* gA0 = A  + (size_t)(bm+r0)*KP + c0*8;
  const _Float16* gA1 = A  + (size_t)(bm+r1)*KP + c1*8;
  const _Float16* gB0 = Bm + (size_t)(bn+r0)*KP + c0*8;
  const _Float16* gB1 = Bm + (size_t)(bn+r1)*KP + c1*8;

  int q = lane>>4, mr = lane&15;
  int m0 = w*32;
  int ra0 = m0+mr, ra1 = m0+16+mr;
  int oa0 = ra0*32 + ((q ^ (ra0&3))*8);
  int oa1 = ra1*32 + ((q ^ (ra1&3))*8);
  int ob[8];
  #pragma unroll
  for (int j=0;j<8;j++){ int rb = j*16+mr; ob[j] = rb*32 + ((q ^ (rb&3))*8); }

  for (int kt=0; kt<KP/32; ++kt){
    __syncthreads();
    __builtin_amdgcn_global_load_lds((glb_uint*)gA0, (lds_uint*)&As[w*1024      ], 16, 0, 0);
    __builtin_amdgcn_global_load_lds((glb_uint*)gA1, (lds_uint*)&As[w*1024 + 512], 16, 0, 0);
    __builtin_amdgcn_global_load_lds((glb_uint*)gB0, (lds_uint*)&Bs[w*1024      ], 16, 0, 0);
    __builtin_amdgcn_global_load_lds((glb_uint*)gB1, (lds_uint*)&Bs[w*1024 + 512], 16, 0, 0);
    gA0 += 32; gA1 += 32; gB0 += 32; gB1 += 32;
    __syncthreads();
    half8 af0 = *(const half8*)&As[oa0];
    half8 af1 = *(const half8*)&As[oa1];
    #pragma unroll
    for (int j=0;j<8;j++){
      half8 bf = *(const half8*)&Bs[ob[j]];
      acc[0][j] = __builtin_amdgcn_mfma_f32_16x16x32_f16(af0, bf, acc[0][j], 0,0,0);
      acc[1][j] = __builtin_amdgcn_mfma_f32_16x16x32_f16(af1, bf, acc[1][j], 0,0,0);
    }
  }
  // epilogue: C/D layout col=lane&15, row=(lane>>4)*4+reg
  #pragma unroll
  for (int j=0;j<8;j++){
    int gc = bn + j*16 + mr;
    float bv = bias[gc];
    #pragma unroll
    for (int i=0;i<2;i++){
      int gr0 = bm + w*32 + i*16 + q*4;
      #pragma unroll
      for (int reg=0; reg<4; ++reg)
        C[(size_t)(gr0+reg)*G4 + gc] = acc[i][j][reg] + bv;
    }
  }
}

// ---------------- phase 2: recurrence, one block per batch row ----------------
// 1024 threads = 16 waves/CU. Thread pair (2r,2r+1) splits gate row r's dot over K
// (32 half2 VGPRs each -> no AGPR eviction); halves combined with one shfl_xor.
// Gates staged as gsh[g*128+d] (conflict-free scalar reads).
__global__ __launch_bounds__(1024,4) void lstm_rec(const float* __restrict__ xg, const unsigned int* __restrict__ Whh2,
     const float* __restrict__ fcw, const float* __restrict__ fcb, float* __restrict__ out){
  int tid = threadIdx.x;           // 0..1023
  int b = blockIdx.x;
  int r = tid >> 1;                // gate row 0..511 (g = r>>7 wave-uniform)
  int s = tid & 1;                 // K-half
  int d = r & 127;
  h2v w[32];
  #pragma unroll
  for (int k=0; k<32; ++k) w[k] = as_h2(Whh2[r*64 + s*32 + k]);

  __shared__ __align__(16) unsigned short hsh[128];
  __shared__ float gsh[512];       // [g*128 + d]
  __shared__ float red[128];
  if (tid < 128) hsh[tid] = 0;
  float creg = 0.f, hreg = 0.f;
  const float* xrow = xg + (size_t)b * (Tt*G4);
  float xc = xrow[r];              // pairs read same addr (L1/L2 broadcast)
  __syncthreads();

  for (int t=0; t<Tt; ++t){
    float xn = 0.f;
    if (t < Tt-1) xn = xrow[(size_t)(t+1)*G4 + r];
    float a0 = (s==0) ? xc : 0.f, a1 = 0.f;
    const uint4* hv = ((const uint4*)hsh) + s*8;   // 2 distinct addrs/wave -> broadcast
    #pragma unroll
    for (int kq=0; kq<8; ++kq){
      uint4 hq = hv[kq];
      a0 = FDOT2(as_h2(hq.x), w[kq*4+0], a0);
      a1 = FDOT2(as_h2(hq.y), w[kq*4+1], a1);
      a0 = FDOT2(as_h2(hq.z), w[kq*4+2], a0);
      a1 = FDOT2(as_h2(hq.w), w[kq*4+3], a1);
    }
    float a = a0 + a1;
    a += __shfl_xor(a, 1, 64);     // combine the two K-halves
    float act;
    if ((r >> 7) == 2){ float e = __expf(2.f*a); act = 1.f - 2.f/(e+1.f); }   // tanh (gate g)
    else              { act = 1.f/(1.f+__expf(-a)); }                          // sigmoid
    if (s == 0) gsh[r] = act;
    __syncthreads();
    float gi = gsh[d], gf = gsh[128+d], gg = gsh[256+d], go = gsh[384+d];
    creg = gf*creg + gi*gg;
    float ec = __expf(2.f*creg); float tc = 1.f - 2.f/(ec+1.f);
    hreg = go*tc;
    if (tid < 256 && s == 0){      // r<128, one writer per d
      union{ _Float16 f; unsigned short u; } cv; cv.f = (_Float16)hreg;
      hsh[r] = cv.u;
    }
    __syncthreads();
    xc = xn;
  }

  // fused FC: out[b] = sum_d h_d * fcw[d] + fcb
  if (tid < 256 && s == 0) red[r] = hreg * fcw[r];
  __syncthreads();
  #pragma unroll
  for (int st=64; st>=1; st>>=1){
    if (tid < st) red[tid] += red[tid+st];
    __syncthreads();
  }
  if (tid == 0) out[b] = red[0] + fcb[0];
}

extern "C" void kernel_launch(void* const* d_in, const int* in_sizes, int n_in,
                              void* d_out, int out_size, void* d_ws, size_t ws_size,
                              hipStream_t stream){
  const float* x   = (const float*)d_in[0];
  const float* Wih = (const float*)d_in[1];
  const float* Whh = (const float*)d_in[2];
  const float* bih = (const float*)d_in[3];
  const float* bhh = (const float*)d_in[4];
  const float* fcw = (const float*)d_in[5];
  const float* fcb = (const float*)d_in[6];
  float* out = (float*)d_out;
  char* ws = (char*)d_ws;

  // ws layout (bytes):
  //   x16  : 0          .. 83,886,080   (131072*320 f16)
  //   W16  : 83,886,080 .. +327,680     (512*320 f16)
  //   Whh2 : 84,213,760 .. +131,072     (512*64 half2)
  //   bias : 84,344,832 .. +2,048       (512 f32)
  //   xg   : 84,346,880 .. +268,435,456 (131072*512 f32)
  unsigned int* x16   = (unsigned int*)(ws);
  unsigned int* W16   = (unsigned int*)(ws + 83886080);
  unsigned int* Whh2w = (unsigned int*)(ws + 84213760);
  float*        bias  = (float*)      (ws + 84344832);
  float*        xg    = (float*)      (ws + 84346880);

  hipLaunchKernelGGL(conv_x,     dim3(81920),  dim3(256), 0, stream, x, x16);
  hipLaunchKernelGGL(conv_small, dim3(450),    dim3(256), 0, stream, Wih, Whh, bih, bhh, W16, Whh2w, bias);
  hipLaunchKernelGGL(gemm16,     dim3(1024,4), dim3(256), 0, stream,
                     (const _Float16*)x16, (const _Float16*)W16, bias, xg);
  hipLaunchKernelGGL(lstm_rec,   dim3(256),    dim3(1024), 0, stream, xg, Whh2w, fcw, fcb, out);
}